// Round 1
// baseline (198.660 us; speedup 1.0000x reference)
//
#include <hip/hip_runtime.h>

// VQ-VAE vector quantizer, fp32 VALU implementation.
// inputs: d_in[0] = inputs [16,64,64,64] NCHW fp32, d_in[1] = embedding [1024,64] fp32
// out layout (fp32, concatenated): [ loss(1) | quantized NCHW (4194304) | indices as float (65536) ]

#define DIMS   64
#define HW     4096      // 64*64
#define NPTS   65536     // 16*4096
#define NCODES 1024
#define NP     128       // points per block
#define KC     64        // codes per chunk
#define NCH    16        // 1024/64
#define QOFF   1
#define IOFF   (1 + 16 * DIMS * HW)   // 1 + 4194304

__launch_bounds__(256, 3)
__global__ void vq_main(const float* __restrict__ in, const float* __restrict__ emb,
                        float* __restrict__ out)
{
    // LDS: Xs [64][128] (8192 f) | Es [64][65] (4160 f) | esqs [64] -> 49664 B, 3 blocks/CU
    __shared__ float smem[12416];
    float* Xs   = smem;                 // X tile, [d][p], stride 128
    float* Es   = smem + 8192;          // E chunk, [c][d], stride 65 (odd pad)
    float* esqs = smem + 8192 + 4160;   // per-chunk ||e||^2

    const int tid = threadIdx.x;
    const int col = tid & 15;           // 16 code-columns
    const int row = tid >> 4;           // 16 point-rows
    const int c0  = col * 4;            // 4 codes / thread / chunk
    const int p0  = row * 8;            // 8 points / thread

    const int n0  = blockIdx.x * NP;
    const int b   = n0 >> 12;           // batch (128 | 4096, never crosses)
    const int off = n0 & 4095;

    // ---- stage X tile: NCHW is [d][p]-contiguous per batch -> direct coalesced copy
    const float4* inb = reinterpret_cast<const float4*>(in + (size_t)b * (DIMS * HW) + off);
    #pragma unroll
    for (int i = 0; i < 8; ++i) {
        int idx = tid + i * 256;        // 0..2047 float4s
        int d = idx >> 5, p4 = idx & 31;
        float4 v = inb[d * (HW / 4) + p4];
        *reinterpret_cast<float4*>(&Xs[d * 128 + p4 * 4]) = v;
    }

    float minv[8];
    int   mini[8];
    #pragma unroll
    for (int i = 0; i < 8; ++i) { minv[i] = 3.0e38f; mini[i] = 0; }

    for (int ch = 0; ch < NCH; ++ch) {
        const int k0 = ch * KC;
        __syncthreads();                // Es readers from previous chunk done
        // ---- stage E chunk (contiguous 64x64 floats), coalesced float4 reads
        const float4* eb = reinterpret_cast<const float4*>(emb + k0 * DIMS);
        #pragma unroll
        for (int i = 0; i < 4; ++i) {
            int idx = tid + i * 256;    // 0..1023 float4s
            int c = idx >> 4, q = idx & 15;
            float4 v = eb[idx];
            float* dst = &Es[c * 65 + q * 4];
            dst[0] = v.x; dst[1] = v.y; dst[2] = v.z; dst[3] = v.w;
        }
        __syncthreads();
        // ---- per-chunk ||e||^2: 4 threads per code, shuffle-reduce width 4
        {
            const int c = tid >> 2, q = tid & 3;
            const float* er = &Es[c * 65 + q * 16];
            float s = 0.f;
            #pragma unroll
            for (int i = 0; i < 16; ++i) s = fmaf(er[i], er[i], s);
            s += __shfl_down(s, 2, 4);
            s += __shfl_down(s, 1, 4);
            if (q == 0) esqs[c] = s;
        }
        __syncthreads();

        // ---- 128x64 dot tile: 8 points x 4 codes per thread, fp32 FMA
        float acc[8][4];
        #pragma unroll
        for (int i = 0; i < 8; ++i)
            #pragma unroll
            for (int j = 0; j < 4; ++j) acc[i][j] = 0.f;

        #pragma unroll 4
        for (int dd = 0; dd < DIMS; ++dd) {
            float4 xa = *reinterpret_cast<const float4*>(&Xs[dd * 128 + p0]);
            float4 xb = *reinterpret_cast<const float4*>(&Xs[dd * 128 + p0 + 4]);
            float e0 = Es[(c0 + 0) * 65 + dd];
            float e1 = Es[(c0 + 1) * 65 + dd];
            float e2 = Es[(c0 + 2) * 65 + dd];
            float e3 = Es[(c0 + 3) * 65 + dd];
            float x[8] = {xa.x, xa.y, xa.z, xa.w, xb.x, xb.y, xb.z, xb.w};
            #pragma unroll
            for (int i = 0; i < 8; ++i) {
                acc[i][0] = fmaf(x[i], e0, acc[i][0]);
                acc[i][1] = fmaf(x[i], e1, acc[i][1]);
                acc[i][2] = fmaf(x[i], e2, acc[i][2]);
                acc[i][3] = fmaf(x[i], e3, acc[i][3]);
            }
        }

        // ---- running argmin of (||e||^2 - 2 x.e); strict < + ascending k keeps first-min
        #pragma unroll
        for (int j = 0; j < 4; ++j) {
            float eq = esqs[c0 + j];
            int k = k0 + c0 + j;
            #pragma unroll
            for (int i = 0; i < 8; ++i) {
                float dist = fmaf(-2.f, acc[i][j], eq);
                if (dist < minv[i]) { minv[i] = dist; mini[i] = k; }
            }
        }
    }

    // ---- cross-column argmin reduce (reuse Es region)
    __syncthreads();
    float* redv  = Es;                              // [128][16]
    int*   redi  = reinterpret_cast<int*>(Es + 2048);
    float* lossb = Es + 4096;                       // [128] (spills into dead esqs)
    #pragma unroll
    for (int i = 0; i < 8; ++i) {
        int p = p0 + i;
        redv[p * 16 + col] = minv[i];
        redi[p * 16 + col] = mini[i];
    }
    __syncthreads();

    if (tid < NP) {
        const int p = tid;
        float bv = redv[p * 16];
        int   bi = redi[p * 16];
        #pragma unroll
        for (int c = 1; c < 16; ++c) {
            float v  = redv[p * 16 + c];
            int   id = redi[p * 16 + c];
            if (v < bv || (v == bv && id < bi)) { bv = v; bi = id; }
        }
        const int n = n0 + p;
        out[IOFF + n] = (float)bi;                  // indices emitted as float
        const float* e = emb + bi * DIMS;
        float* oq = out + QOFF + (size_t)b * (DIMS * HW) + off + p;
        float lsum = 0.f;
        #pragma unroll 8
        for (int c = 0; c < DIMS; ++c) {
            float ev = e[c];                        // gather (L2-resident, 256 KB table)
            float xv = Xs[c * 128 + p];
            float df = ev - xv;
            lsum = fmaf(df, df, lsum);
            oq[c * HW] = ev;                        // coalesced across threads
        }
        lossb[p] = lsum;
    }
    __syncthreads();
    if (tid == 0) {
        float s = 0.f;
        for (int i = 0; i < NP; ++i) s += lossb[i];
        atomicAdd(out, s * (0.25f / (float)(16 * DIMS * HW)));
    }
}

extern "C" void kernel_launch(void* const* d_in, const int* in_sizes, int n_in,
                              void* d_out, int out_size, void* d_ws, size_t ws_size,
                              hipStream_t stream) {
    const float* in  = (const float*)d_in[0];
    const float* emb = (const float*)d_in[1];
    float* out = (float*)d_out;
    (void)d_ws; (void)ws_size; (void)in_sizes; (void)n_in; (void)out_size;

    // loss is accumulated with atomics -> zero it (d_out is poisoned 0xAA each launch)
    hipMemsetAsync(d_out, 0, sizeof(float), stream);
    vq_main<<<NPTS / NP, 256, 0, stream>>>(in, emb, out);
}